// Round 2
// baseline (582.442 us; speedup 1.0000x reference)
//
#include <hip/hip_runtime.h>

#define THREADS 256

// ws[0] = sum over edges of (1-p_u)(1-p_v) for u!=v   (double)
// ws[1] = sum over nodes of probs                      (double)

__device__ __forceinline__ void block_reduce_atomic(float local, double* dst,
                                                    double* sdata) {
    double d = (double)local;
    #pragma unroll
    for (int off = 32; off > 0; off >>= 1)
        d += __shfl_down(d, off, 64);
    int lane = threadIdx.x & 63;
    int wid  = threadIdx.x >> 6;
    if (lane == 0) sdata[wid] = d;
    __syncthreads();
    if (threadIdx.x == 0) {
        double s = 0.0;
        #pragma unroll
        for (int i = 0; i < THREADS / 64; ++i) s += sdata[i];
        atomicAdd(dst, s);
    }
}

__global__ void __launch_bounds__(THREADS) edge_sum_kernel(
        const float* __restrict__ probs,
        const int* __restrict__ row,
        const int* __restrict__ col,
        double* __restrict__ ws,
        long long n_edges) {
    __shared__ double sdata[THREADS / 64];
    long long tid = (long long)blockIdx.x * blockDim.x + threadIdx.x;
    long long stride = (long long)gridDim.x * blockDim.x;

    const int4* row4 = (const int4*)row;
    const int4* col4 = (const int4*)col;
    long long n4 = n_edges >> 2;  // 32M edges divisible by 4

    float local = 0.0f;
    for (long long i = tid; i < n4; i += stride) {
        int4 u = row4[i];
        int4 v = col4[i];
        float a0 = 1.0f - probs[u.x], b0 = 1.0f - probs[v.x];
        float a1 = 1.0f - probs[u.y], b1 = 1.0f - probs[v.y];
        float a2 = 1.0f - probs[u.z], b2 = 1.0f - probs[v.z];
        float a3 = 1.0f - probs[u.w], b3 = 1.0f - probs[v.w];
        local += (u.x != v.x) ? a0 * b0 : 0.0f;
        local += (u.y != v.y) ? a1 * b1 : 0.0f;
        local += (u.z != v.z) ? a2 * b2 : 0.0f;
        local += (u.w != v.w) ? a3 * b3 : 0.0f;
    }
    // tail
    for (long long e = (n4 << 2) + tid; e < n_edges; e += stride) {
        int u = row[e], v = col[e];
        float t = (1.0f - probs[u]) * (1.0f - probs[v]);
        local += (u != v) ? t : 0.0f;
    }

    block_reduce_atomic(local, ws, sdata);
}

__global__ void __launch_bounds__(THREADS) prob_sum_kernel(
        const float* __restrict__ probs,
        double* __restrict__ ws,
        long long n_nodes) {
    __shared__ double sdata[THREADS / 64];
    long long n4 = n_nodes >> 2;
    const float4* p4 = (const float4*)probs;
    long long tid = (long long)blockIdx.x * blockDim.x + threadIdx.x;
    long long stride = (long long)gridDim.x * blockDim.x;

    float local = 0.0f;
    for (long long i = tid; i < n4; i += stride) {
        float4 v = p4[i];
        local += (v.x + v.y) + (v.z + v.w);
    }
    for (long long i = (n4 << 2) + tid; i < n_nodes; i += stride)
        local += probs[i];

    block_reduce_atomic(local, ws + 1, sdata);
}

__global__ void finalize_kernel(const double* __restrict__ ws,
                                const int* __restrict__ batch,
                                long long n_nodes,
                                const float* __restrict__ pc,
                                float* __restrict__ out) {
    double edge_s = ws[0];
    double prob_s = ws[1];
    double G = (double)(batch[n_nodes - 1] + 1);  // batch is sorted
    double ed = edge_s / G;
    double ew = prob_s / G;
    double loss = (double)pc[0] * ed + ew;
    out[0] = (float)loss;
    out[1] = (float)ew;
    out[2] = (float)ed;
}

extern "C" void kernel_launch(void* const* d_in, const int* in_sizes, int n_in,
                              void* d_out, int out_size, void* d_ws, size_t ws_size,
                              hipStream_t stream) {
    const float* probs = (const float*)d_in[0];
    const int* edge_index = (const int*)d_in[1];   // harness passes integers as int32
    const int* batch = (const int*)d_in[2];
    const float* pc = (const float*)d_in[3];

    long long n_nodes = (long long)in_sizes[0];
    long long n_edges = (long long)in_sizes[1] / 2;
    const int* row = edge_index;
    const int* col = edge_index + n_edges;

    double* ws = (double*)d_ws;
    hipMemsetAsync(ws, 0, 2 * sizeof(double), stream);

    // Edge reduction: memory-bound; cap grid, grid-stride the rest.
    int edge_blocks = 2048;
    edge_sum_kernel<<<edge_blocks, THREADS, 0, stream>>>(probs, row, col, ws, n_edges);

    int prob_blocks = 512;
    prob_sum_kernel<<<prob_blocks, THREADS, 0, stream>>>(probs, ws, n_nodes);

    finalize_kernel<<<1, 1, 0, stream>>>(ws, batch, n_nodes, pc, (float*)d_out);
}

// Round 3
// 322.147 us; speedup vs baseline: 1.8080x; 1.8080x over previous
//
#include <hip/hip_runtime.h>
#include <hip/hip_fp16.h>

#define THREADS 256

// ws layout:
//   ws[0] (double)  = sum over edges of (1-p_u)(1-p_v) for u!=v
//   ws[1] (double)  = sum over nodes of probs
//   byte offset 256 = fp16 table q[i] = 1 - probs[i]  (N_NODES * 2 bytes)

__device__ __forceinline__ void block_reduce_atomic(float local, double* dst,
                                                    double* sdata) {
    double d = (double)local;
    #pragma unroll
    for (int off = 32; off > 0; off >>= 1)
        d += __shfl_down(d, off, 64);
    int lane = threadIdx.x & 63;
    int wid  = threadIdx.x >> 6;
    if (lane == 0) sdata[wid] = d;
    __syncthreads();
    if (threadIdx.x == 0) {
        double s = 0.0;
        #pragma unroll
        for (int i = 0; i < THREADS / 64; ++i) s += sdata[i];
        atomicAdd(dst, s);
    }
}

// Build q = 1 - p as fp16 table; fused: also reduce sum(probs).
__global__ void __launch_bounds__(THREADS) build_table_kernel(
        const float* __restrict__ probs,
        __half* __restrict__ qt,
        double* __restrict__ ws,
        long long n_nodes) {
    __shared__ double sdata[THREADS / 64];
    long long n4 = n_nodes >> 2;
    const float4* p4 = (const float4*)probs;
    ushort4* q4 = (ushort4*)qt;
    long long tid = (long long)blockIdx.x * blockDim.x + threadIdx.x;
    long long stride = (long long)gridDim.x * blockDim.x;

    float local = 0.0f;
    for (long long i = tid; i < n4; i += stride) {
        float4 v = p4[i];
        local += (v.x + v.y) + (v.z + v.w);
        ushort4 q;
        q.x = __half_as_ushort(__float2half(1.0f - v.x));
        q.y = __half_as_ushort(__float2half(1.0f - v.y));
        q.z = __half_as_ushort(__float2half(1.0f - v.z));
        q.w = __half_as_ushort(__float2half(1.0f - v.w));
        q4[i] = q;
    }
    for (long long i = (n4 << 2) + tid; i < n_nodes; i += stride) {
        float p = probs[i];
        local += p;
        qt[i] = __float2half(1.0f - p);
    }

    block_reduce_atomic(local, ws + 1, sdata);
}

__global__ void __launch_bounds__(THREADS) edge_sum_kernel(
        const __half* __restrict__ qt,
        const int* __restrict__ row,
        const int* __restrict__ col,
        double* __restrict__ ws,
        long long n_edges) {
    __shared__ double sdata[THREADS / 64];
    long long tid = (long long)blockIdx.x * blockDim.x + threadIdx.x;
    long long stride = (long long)gridDim.x * blockDim.x;

    const int4* row4 = (const int4*)row;
    const int4* col4 = (const int4*)col;
    long long n4 = n_edges >> 2;  // 32M edges divisible by 4

    float local = 0.0f;
    for (long long i = tid; i < n4; i += stride) {
        int4 u = row4[i];
        int4 v = col4[i];
        float a0 = __half2float(qt[u.x]), b0 = __half2float(qt[v.x]);
        float a1 = __half2float(qt[u.y]), b1 = __half2float(qt[v.y]);
        float a2 = __half2float(qt[u.z]), b2 = __half2float(qt[v.z]);
        float a3 = __half2float(qt[u.w]), b3 = __half2float(qt[v.w]);
        local += (u.x != v.x) ? a0 * b0 : 0.0f;
        local += (u.y != v.y) ? a1 * b1 : 0.0f;
        local += (u.z != v.z) ? a2 * b2 : 0.0f;
        local += (u.w != v.w) ? a3 * b3 : 0.0f;
    }
    for (long long e = (n4 << 2) + tid; e < n_edges; e += stride) {
        int u = row[e], v = col[e];
        float t = __half2float(qt[u]) * __half2float(qt[v]);
        local += (u != v) ? t : 0.0f;
    }

    block_reduce_atomic(local, ws, sdata);
}

// Fallback (no workspace room): gather fp32 probs directly.
__global__ void __launch_bounds__(THREADS) edge_sum_f32_kernel(
        const float* __restrict__ probs,
        const int* __restrict__ row,
        const int* __restrict__ col,
        double* __restrict__ ws,
        long long n_edges) {
    __shared__ double sdata[THREADS / 64];
    long long tid = (long long)blockIdx.x * blockDim.x + threadIdx.x;
    long long stride = (long long)gridDim.x * blockDim.x;
    float local = 0.0f;
    for (long long e = tid; e < n_edges; e += stride) {
        int u = row[e], v = col[e];
        float t = (1.0f - probs[u]) * (1.0f - probs[v]);
        local += (u != v) ? t : 0.0f;
    }
    block_reduce_atomic(local, ws, sdata);
}

__global__ void __launch_bounds__(THREADS) prob_sum_kernel(
        const float* __restrict__ probs,
        double* __restrict__ ws,
        long long n_nodes) {
    __shared__ double sdata[THREADS / 64];
    long long n4 = n_nodes >> 2;
    const float4* p4 = (const float4*)probs;
    long long tid = (long long)blockIdx.x * blockDim.x + threadIdx.x;
    long long stride = (long long)gridDim.x * blockDim.x;
    float local = 0.0f;
    for (long long i = tid; i < n4; i += stride) {
        float4 v = p4[i];
        local += (v.x + v.y) + (v.z + v.w);
    }
    for (long long i = (n4 << 2) + tid; i < n_nodes; i += stride)
        local += probs[i];
    block_reduce_atomic(local, ws + 1, sdata);
}

__global__ void finalize_kernel(const double* __restrict__ ws,
                                const int* __restrict__ batch,
                                long long n_nodes,
                                const float* __restrict__ pc,
                                float* __restrict__ out) {
    double edge_s = ws[0];
    double prob_s = ws[1];
    double G = (double)(batch[n_nodes - 1] + 1);  // batch is sorted
    double ed = edge_s / G;
    double ew = prob_s / G;
    double loss = (double)pc[0] * ed + ew;
    out[0] = (float)loss;
    out[1] = (float)ew;
    out[2] = (float)ed;
}

extern "C" void kernel_launch(void* const* d_in, const int* in_sizes, int n_in,
                              void* d_out, int out_size, void* d_ws, size_t ws_size,
                              hipStream_t stream) {
    const float* probs = (const float*)d_in[0];
    const int* edge_index = (const int*)d_in[1];   // harness passes integers as int32
    const int* batch = (const int*)d_in[2];
    const float* pc = (const float*)d_in[3];

    long long n_nodes = (long long)in_sizes[0];
    long long n_edges = (long long)in_sizes[1] / 2;
    const int* row = edge_index;
    const int* col = edge_index + n_edges;

    double* ws = (double*)d_ws;
    hipMemsetAsync(ws, 0, 2 * sizeof(double), stream);

    size_t table_bytes = (size_t)n_nodes * sizeof(__half);
    if (ws_size >= 256 + table_bytes) {
        __half* qt = (__half*)((char*)d_ws + 256);
        build_table_kernel<<<512, THREADS, 0, stream>>>(probs, qt, ws, n_nodes);
        edge_sum_kernel<<<2048, THREADS, 0, stream>>>(qt, row, col, ws, n_edges);
    } else {
        prob_sum_kernel<<<512, THREADS, 0, stream>>>(probs, ws, n_nodes);
        edge_sum_f32_kernel<<<2048, THREADS, 0, stream>>>(probs, row, col, ws, n_edges);
    }
    finalize_kernel<<<1, 1, 0, stream>>>(ws, batch, n_nodes, pc, (float*)d_out);
}

// Round 4
// 303.355 us; speedup vs baseline: 1.9200x; 1.0619x over previous
//
#include <hip/hip_runtime.h>
#include <hip/hip_fp16.h>

#define THREADS 256

typedef int int4v __attribute__((ext_vector_type(4)));

// ws layout:
//   ws[0] (double)  = sum over edges of (1-p_u)(1-p_v) for u!=v
//   ws[1] (double)  = sum over nodes of probs
//   byte offset 256 = fp16 table q[i] = 1 - probs[i]  (N_NODES * 2 bytes)

__device__ __forceinline__ void block_reduce_atomic(float local, double* dst,
                                                    double* sdata) {
    double d = (double)local;
    #pragma unroll
    for (int off = 32; off > 0; off >>= 1)
        d += __shfl_down(d, off, 64);
    int lane = threadIdx.x & 63;
    int wid  = threadIdx.x >> 6;
    if (lane == 0) sdata[wid] = d;
    __syncthreads();
    if (threadIdx.x == 0) {
        double s = 0.0;
        #pragma unroll
        for (int i = 0; i < THREADS / 64; ++i) s += sdata[i];
        atomicAdd(dst, s);
    }
}

// Build q = 1 - p as fp16 table; fused: also reduce sum(probs).
__global__ void __launch_bounds__(THREADS) build_table_kernel(
        const float* __restrict__ probs,
        __half* __restrict__ qt,
        double* __restrict__ ws,
        long long n_nodes) {
    __shared__ double sdata[THREADS / 64];
    long long n4 = n_nodes >> 2;
    const float4* p4 = (const float4*)probs;
    ushort4* q4 = (ushort4*)qt;
    long long tid = (long long)blockIdx.x * blockDim.x + threadIdx.x;
    long long stride = (long long)gridDim.x * blockDim.x;

    float local = 0.0f;
    for (long long i = tid; i < n4; i += stride) {
        float4 v = p4[i];
        local += (v.x + v.y) + (v.z + v.w);
        ushort4 q;
        q.x = __half_as_ushort(__float2half(1.0f - v.x));
        q.y = __half_as_ushort(__float2half(1.0f - v.y));
        q.z = __half_as_ushort(__float2half(1.0f - v.z));
        q.w = __half_as_ushort(__float2half(1.0f - v.w));
        q4[i] = q;
    }
    for (long long i = (n4 << 2) + tid; i < n_nodes; i += stride) {
        float p = probs[i];
        local += p;
        qt[i] = __float2half(1.0f - p);
    }

    block_reduce_atomic(local, ws + 1, sdata);
}

// Exact-cover, 8 edges/thread: maximize gathers in flight (16/lane), no
// grid-stride loop so wave churn sustains MLP.
__global__ void __launch_bounds__(THREADS) edge_sum_kernel(
        const __half* __restrict__ qt,
        const int* __restrict__ row,
        const int* __restrict__ col,
        double* __restrict__ ws,
        long long n_edges) {
    __shared__ double sdata[THREADS / 64];
    long long n4 = n_edges >> 2;   // int4 groups
    long long T  = n4 >> 1;        // threads in main part (2 groups each)
    long long t  = (long long)blockIdx.x * blockDim.x + threadIdx.x;

    const int4v* row4 = (const int4v*)row;
    const int4v* col4 = (const int4v*)col;

    float local = 0.0f;
    if (t < T) {
        // 4 coalesced dwordx4 index loads, non-temporal (streamed once)
        int4v u0 = __builtin_nontemporal_load(&row4[t]);
        int4v v0 = __builtin_nontemporal_load(&col4[t]);
        int4v u1 = __builtin_nontemporal_load(&row4[t + T]);
        int4v v1 = __builtin_nontemporal_load(&col4[t + T]);

        // 16 independent gathers — all issued before first use
        __half a0 = qt[u0.x], b0 = qt[v0.x];
        __half a1 = qt[u0.y], b1 = qt[v0.y];
        __half a2 = qt[u0.z], b2 = qt[v0.z];
        __half a3 = qt[u0.w], b3 = qt[v0.w];
        __half a4 = qt[u1.x], b4 = qt[v1.x];
        __half a5 = qt[u1.y], b5 = qt[v1.y];
        __half a6 = qt[u1.z], b6 = qt[v1.z];
        __half a7 = qt[u1.w], b7 = qt[v1.w];

        local += (u0.x != v0.x) ? __half2float(a0) * __half2float(b0) : 0.0f;
        local += (u0.y != v0.y) ? __half2float(a1) * __half2float(b1) : 0.0f;
        local += (u0.z != v0.z) ? __half2float(a2) * __half2float(b2) : 0.0f;
        local += (u0.w != v0.w) ? __half2float(a3) * __half2float(b3) : 0.0f;
        local += (u1.x != v1.x) ? __half2float(a4) * __half2float(b4) : 0.0f;
        local += (u1.y != v1.y) ? __half2float(a5) * __half2float(b5) : 0.0f;
        local += (u1.z != v1.z) ? __half2float(a6) * __half2float(b6) : 0.0f;
        local += (u1.w != v1.w) ? __half2float(a7) * __half2float(b7) : 0.0f;
    }

    // tail: edges not covered by the 8-per-thread main part
    long long covered = T << 3;
    long long total_threads = (long long)gridDim.x * blockDim.x;
    for (long long e = covered + t; e < n_edges; e += total_threads) {
        int u = row[e], v = col[e];
        float tt = __half2float(qt[u]) * __half2float(qt[v]);
        local += (u != v) ? tt : 0.0f;
    }

    block_reduce_atomic(local, ws, sdata);
}

__global__ void finalize_kernel(const double* __restrict__ ws,
                                const int* __restrict__ batch,
                                long long n_nodes,
                                const float* __restrict__ pc,
                                float* __restrict__ out) {
    double edge_s = ws[0];
    double prob_s = ws[1];
    double G = (double)(batch[n_nodes - 1] + 1);  // batch is sorted
    double ed = edge_s / G;
    double ew = prob_s / G;
    double loss = (double)pc[0] * ed + ew;
    out[0] = (float)loss;
    out[1] = (float)ew;
    out[2] = (float)ed;
}

extern "C" void kernel_launch(void* const* d_in, const int* in_sizes, int n_in,
                              void* d_out, int out_size, void* d_ws, size_t ws_size,
                              hipStream_t stream) {
    const float* probs = (const float*)d_in[0];
    const int* edge_index = (const int*)d_in[1];   // harness passes integers as int32
    const int* batch = (const int*)d_in[2];
    const float* pc = (const float*)d_in[3];

    long long n_nodes = (long long)in_sizes[0];
    long long n_edges = (long long)in_sizes[1] / 2;
    const int* row = edge_index;
    const int* col = edge_index + n_edges;

    double* ws = (double*)d_ws;
    hipMemsetAsync(ws, 0, 2 * sizeof(double), stream);

    __half* qt = (__half*)((char*)d_ws + 256);
    build_table_kernel<<<512, THREADS, 0, stream>>>(probs, qt, ws, n_nodes);

    long long T = (n_edges >> 2) >> 1;           // main-part threads
    long long blocks = (T + THREADS - 1) / THREADS;
    if (blocks < 1) blocks = 1;
    edge_sum_kernel<<<(int)blocks, THREADS, 0, stream>>>(qt, row, col, ws, n_edges);

    finalize_kernel<<<1, 1, 0, stream>>>(ws, batch, n_nodes, pc, (float*)d_out);
}